// Round 9
// baseline (120.033 us; speedup 1.0000x reference)
//
#include <hip/hip_runtime.h>
#include <hip/hip_bf16.h>

// Problem constants: B=4, G=3, p=16, N=256, C=768, H=12, D=64
#define Bc 4
#define Gc 3
#define Nc 256
#define Cc_ 768
#define Dc 64
#define Mrows (Bc*Gc*Nc)      // 3072 tokens
#define QKVc (3*Cc_)          // 2304 fused output cols: [q | k | v]
#define Koff Cc_              // k starts at col 768
#define Voff (2*Cc_)          // v starts at col 1536

typedef _Float16 half_t;
typedef __attribute__((ext_vector_type(8))) _Float16 f16x8;
typedef __attribute__((ext_vector_type(4))) float f32x4;

__device__ inline f16x8 cv8(const float4& x, const float4& y) {
    f16x8 o;
    o[0] = (half_t)x.x; o[1] = (half_t)x.y; o[2] = (half_t)x.z; o[3] = (half_t)x.w;
    o[4] = (half_t)y.x; o[5] = (half_t)y.y; o[6] = (half_t)y.z; o[7] = (half_t)y.w;
    return o;
}

// ---------------------------------------------------------------------------
// Mixed-precision MFMA GEMM:  C[m][n] = sum_k A[m][k]*W[n][k]  (+ bias[n])
// A_F32/W_F32 select fp32 inputs, converted to f16 IN the staging path
// (reg-stage: global_load_dwordx4 -> v_cvt -> ds_write_b128) — this removes
// the separate cvt kernel (dispatch overhead was the r8 post-mortem finding).
// W is split across two buffers at row `wsplit` (wq rows 0-767, wkv rows
// 768-2303); tiles are 128-aligned and wsplit=768=6*128, so the base-pointer
// select is block-uniform.
// 128x128 tile, BK=32, 256 thr = 4 waves (2x2 of 64x64), mfma 16x16x32.
// Pipeline: 2 LDS buffers, 1 barrier/iter, single staging reg-set:
//   sync -> compute(cur) -> swrite(cur^1 <- tile t+1) -> gload(tile t+2)
// swrite's vmcnt wait on gload(t+1) has a full iteration of slack; the
// barrier's vmcnt(0) drain of gload(t+2) lands after compute+swrite.
// ---------------------------------------------------------------------------
template<bool A_F32, bool W_F32, typename OutT, bool BIAS>
__global__ __launch_bounds__(256) void gemm16(
    const void* __restrict__ Av, const void* __restrict__ W1v,
    const void* __restrict__ W2v, int wsplit,
    OutT* __restrict__ C, const float* __restrict__ bias,
    int M, int Nn, int K)
{
    // [buf][kgroup][row][8 f16] per matrix = 16 KiB each, 32 KiB total
    __shared__ __attribute__((aligned(16))) half_t smA[2][4][128][8];
    __shared__ __attribute__((aligned(16))) half_t smB[2][4][128][8];

    const int tid = threadIdx.x;
    const int w   = tid >> 6;          // wave 0..3
    const int l   = tid & 63;
    const int wm  = w >> 1;            // m sub-tile
    const int wn  = w & 1;             // n sub-tile
    const int m0  = blockIdx.y << 7;
    const int n0  = blockIdx.x << 7;

    // block-uniform W base select (tile never straddles wsplit)
    const void* Wv; int nrow0;
    if (n0 < wsplit) { Wv = W1v; nrow0 = n0; }
    else             { Wv = W2v; nrow0 = n0 - wsplit; }

    // staging assignment: thread -> (rows tid&127, kgroups (tid>>7)*2 + q)
    const int srow = tid & 127;
    const int skg0 = (tid >> 7) << 1;

    float4 raf[2][2], rbf[2][2];       // fp32 staging regs (unused -> DCE'd)
    f16x8  rah[2],    rbh[2];          // f16 staging regs

    auto gload = [&](int k0) {
        #pragma unroll
        for (int q = 0; q < 2; ++q) {
            const int kg = skg0 + q;
            const size_t ia = (size_t)(m0 + srow) * K + k0 + kg * 8;
            const size_t ib = (size_t)(nrow0 + srow) * K + k0 + kg * 8;
            if constexpr (A_F32) {
                const float* p = (const float*)Av + ia;
                raf[q][0] = *(const float4*)p; raf[q][1] = *(const float4*)(p + 4);
            } else {
                rah[q] = *(const f16x8*)((const half_t*)Av + ia);
            }
            if constexpr (W_F32) {
                const float* p = (const float*)Wv + ib;
                rbf[q][0] = *(const float4*)p; rbf[q][1] = *(const float4*)(p + 4);
            } else {
                rbh[q] = *(const f16x8*)((const half_t*)Wv + ib);
            }
        }
    };
    auto swrite = [&](int buf) {
        #pragma unroll
        for (int q = 0; q < 2; ++q) {
            const int kg = skg0 + q;
            f16x8 oa, ob;
            if constexpr (A_F32) oa = cv8(raf[q][0], raf[q][1]); else oa = rah[q];
            if constexpr (W_F32) ob = cv8(rbf[q][0], rbf[q][1]); else ob = rbh[q];
            *(f16x8*)&smA[buf][kg][srow][0] = oa;
            *(f16x8*)&smB[buf][kg][srow][0] = ob;
        }
    };

    f32x4 acc[4][4] = {};

    const int NT = K >> 5;             // 24 for K=768
    gload(0);  swrite(0);              // tile 0 -> buf 0
    gload(32);                         // tile 1 in regs (in flight)

    const int kg = l >> 4;             // 0..3
    const int lr = l & 15;
    int cur = 0;

    for (int t = 0; t < NT; ++t) {
        __syncthreads();               // buf[cur] written; prev reads done

        f16x8 af[4], bf[4];
        #pragma unroll
        for (int mi = 0; mi < 4; ++mi)
            af[mi] = *(const f16x8*)&smA[cur][kg][wm * 64 + mi * 16 + lr][0];
        #pragma unroll
        for (int ni = 0; ni < 4; ++ni)
            bf[ni] = *(const f16x8*)&smB[cur][kg][wn * 64 + ni * 16 + lr][0];

        #pragma unroll
        for (int mi = 0; mi < 4; ++mi)
            #pragma unroll
            for (int ni = 0; ni < 4; ++ni)
                acc[mi][ni] = __builtin_amdgcn_mfma_f32_16x16x32_f16(
                    af[mi], bf[ni], acc[mi][ni], 0, 0, 0);

        if (t + 1 < NT) {
            swrite(cur ^ 1);                    // tile t+1 -> other buffer
            if (t + 2 < NT) gload((t + 2) << 5); // issue next loads
        }
        cur ^= 1;
    }

    // epilogue: C/D layout col = lane&15, row = (lane>>4)*4 + reg (m89)
    const int lq = l >> 4;
    #pragma unroll
    for (int ni = 0; ni < 4; ++ni) {
        const int gcol = n0 + wn * 64 + ni * 16 + lr;
        const float bv = BIAS ? bias[gcol] : 0.f;
        #pragma unroll
        for (int mi = 0; mi < 4; ++mi) {
            const int grow = m0 + wm * 64 + mi * 16 + lq * 4;
            #pragma unroll
            for (int r = 0; r < 4; ++r)
                C[(size_t)(grow + r) * Nn + gcol] = (OutT)(acc[mi][ni][r] + bv);
        }
    }
}

// ---------------------------------------------------------------------------
// Attention (round-6 verbatim — best known config): one block (4 waves) per
// token t=(g*B+b)*N+n; wave handles heads {w, w+4, w+8}. Q/K/V from the
// fused QKV buffer (f16, fp32 math); K/V gathered via the triplane map.
// ---------------------------------------------------------------------------
__global__ __launch_bounds__(256) void attn_kernel(
    const half_t* __restrict__ QKV,  // (Mrows, 2304) f16 x-order; [q|k|v]
    half_t* __restrict__ Oa)         // (Mrows, C) f16, out-order rows (g,b,n)
{
    const int t  = blockIdx.x;
    const int g  = t >> 10;
    const int b  = (t >> 8) & 3;
    const int n  = t & 255;
    const int a  = n >> 4;
    const int bc = n & 15;

    __shared__ float qs[Cc_];
    __shared__ int   rows[32];

    const int qrow = (b * Gc + g) * Nc + n;
    if (threadIdx.x < 96) {
        const f16x8 v = ((const f16x8*)(QKV + (size_t)qrow * QKVc))[threadIdx.x];
        #pragma unroll
        for (int jj = 0; jj < 8; ++jj) qs[threadIdx.x * 8 + jj] = (float)v[jj];
    }
    if (threadIdx.x < 32) {
        const int j = threadIdx.x;
        int g1 = g + 1; if (g1 >= 3) g1 -= 3;
        int g2 = g + 2; if (g2 >= 3) g2 -= 3;
        rows[j] = (j < 16) ? ((b * Gc + g1) * Nc + a * 16 + j)
                           : ((b * Gc + g2) * Nc + (j - 16) * 16 + bc);
    }
    __syncthreads();

    const int wave = threadIdx.x >> 6;
    const int lane = threadIdx.x & 63;
    const int j    = lane & 31;
    const int dh   = lane >> 5;
    const size_t kvrow = (size_t)rows[j] * QKVc;

    for (int hh = 0; hh < 3; ++hh) {
        const int h = wave + hh * 4;
        // ---- scores: lane=(j ctx, dh half), vectorized f16 K reads ----
        const f16x8* kp = (const f16x8*)(QKV + kvrow + Koff + h * Dc + dh * 32);
        const float* qp = qs + h * Dc + dh * 32;
        float s = 0.f;
        #pragma unroll
        for (int c = 0; c < 4; ++c) {
            const f16x8 k8 = kp[c];
            #pragma unroll
            for (int e = 0; e < 8; ++e) s = fmaf(qp[c * 8 + e], (float)k8[e], s);
        }
        s += __shfl_xor(s, 32);
        s *= 0.125f;                         // 1/sqrt(64)

        // ---- softmax over 32 ctx (halves identical) ----
        float m = s;
        #pragma unroll
        for (int off = 16; off >= 1; off >>= 1) m = fmaxf(m, __shfl_xor(m, off));
        const float e = __expf(s - m);
        float lsum = e;
        #pragma unroll
        for (int off = 16; off >= 1; off >>= 1) lsum += __shfl_xor(lsum, off);
        const float pr = e / lsum;

        // ---- PV: lane = output dim ----
        float o = 0.f;
        #pragma unroll 8
        for (int jj = 0; jj < 32; ++jj) {
            const float pj = __shfl(pr, jj);
            o = fmaf(pj, (float)QKV[(size_t)rows[jj] * QKVc + Voff + h * Dc + lane], o);
        }
        Oa[(size_t)t * Cc_ + h * Dc + lane] = (half_t)o;
    }
}

extern "C" void kernel_launch(void* const* d_in, const int* in_sizes, int n_in,
                              void* d_out, int out_size, void* d_ws, size_t ws_size,
                              hipStream_t stream) {
    const float* x   = (const float*)d_in[0];
    const float* wq  = (const float*)d_in[1];
    const float* wkv = (const float*)d_in[2];
    const float* pw  = (const float*)d_in[3];
    const float* pb  = (const float*)d_in[4];
    float* out = (float*)d_out;

    // f16 workspace (~19 MB): no converted-input copies anymore
    half_t* QKV16 = (half_t*)d_ws;                 // (3072, 2304)
    half_t* ATT16 = QKV16 + (size_t)Mrows * QKVc;  // (3072, 768)

    const dim3 blk(256);

    // 1. QKV = x @ [wq;wkv]^T — fp32 inputs converted in-staging.
    //    W rows 0-767 from wq, 768-2303 from wkv (block-uniform split).
    gemm16<true, true, half_t, false>
        <<<dim3(QKVc / 128, Mrows / 128), blk, 0, stream>>>(
        x, wq, wkv, Cc_, QKV16, nullptr, Mrows, QKVc, Cc_);

    // 2. attention with gathered K/V, writes out-order rows (f16)
    attn_kernel<<<dim3(Mrows), blk, 0, stream>>>(QKV16, ATT16);

    // 3. out = ATT16 @ pw^T + pb — A is f16, W converted in-staging,
    //    fp32 epilogue straight into d_out
    gemm16<false, true, float, true>
        <<<dim3(Cc_ / 128, Mrows / 128), blk, 0, stream>>>(
        ATT16, pw, pw, Cc_, out, pb, Mrows, Cc_, Cc_);
}